// Round 13
// baseline (302.914 us; speedup 1.0000x reference)
//
#include <hip/hip_runtime.h>
#include <math.h>

#define NEG_SLOPE 0.2f
#define BN_EPS 1e-5f

typedef __bf16 bf16x8 __attribute__((ext_vector_type(8)));
typedef float  f32x4  __attribute__((ext_vector_type(4)));

__device__ __forceinline__ float elu_f(float x){ return x > 0.f ? x : expm1f(x); }
__device__ __forceinline__ float lrelu_f(float x){ return x > 0.f ? x : NEG_SLOPE * x; }

__device__ __forceinline__ float b2f(ushort u){
    union { uint i; float f; } v; v.i = (uint)u << 16; return v.f;
}
__device__ __forceinline__ ushort f2b(float f){
    union { float f; uint i; } v; v.f = f;
    uint r = v.i + 0x7FFFu + ((v.i >> 16) & 1u);   // RTN-even
    return (ushort)(r >> 16);
}

// per-wave int64-vs-int32 detect: one int64 load per lane + ballot.
__device__ __forceinline__ bool detect_f64(const void* ei, int E, long long N)
{
    const long long* p = (const long long*)ei;
    int lane = threadIdx.x & 63;
    long long v = p[lane % max(1, min(2 * E, 64))];
    bool bad = (v < 0 || v >= N);
    return __ballot(bad) == 0ull;
}

__device__ __forceinline__ void get_edge(const void* ei, int e, int E, bool f64, int& s, int& d)
{
    if (e < E) {
        if (f64) { const long long* p = (const long long*)ei; s = (int)p[e]; d = (int)p[E + e]; }
        else     { const int*       p = (const int*)ei;       s = p[e];      d = p[E + e]; }
    } else {
        s = d = e - E;   // self loops appended
    }
}

// ---------------- fused setup: BN fold + transposes + x->bf16 + degree count ----------------
__global__ void setup_kernel(const void* ei, int E, int N, int* deg, int cx,
    const float* __restrict__ x, ushort* __restrict__ xb,
    const float* __restrict__ W1, const float* __restrict__ W2, const float* __restrict__ Wp,
    ushort* __restrict__ wt1, ushort* __restrict__ wt2, ushort* __restrict__ wtp,
    const float* b1, const float* b2, const float* bp,
    const float* g1, const float* be1, const float* m1, const float* v1,
    const float* g2, const float* be2, const float* m2, const float* v2,
    const float* g3, const float* be3, const float* m3, const float* v3,
    float* par)
{
    int b = blockIdx.x, t = threadIdx.x;
    if (b == 0) {
        { float s = g1[t] * rsqrtf(v1[t] + BN_EPS); par[t] = s;        par[256 + t] = b1[t] * s + be1[t] - m1[t] * s; }
        if (t < 64)  { float s = g2[t] * rsqrtf(v2[t] + BN_EPS); par[512 + t] = s;  par[576 + t] = b2[t] * s + be2[t] - m2[t] * s; }
        if (t < 128) { float s = g3[t] * rsqrtf(v3[t] + BN_EPS); par[640 + t] = s;  par[768 + t] = bp[t] * s + be3[t] - m3[t] * s; }
    } else if (b <= 224) {
        int idx = (b - 1) * 256 + t;
        if (idx < 32768) {                       // W1: [128,256] -> wt1[n*128+k]
            int n = idx >> 7, k = idx & 127;
            wt1[idx] = f2b(W1[k * 256 + n]);
        } else if (idx < 49152) {                // W2: [256,64] -> wt2[n*256+k]
            int j = idx - 32768;
            int n = j >> 8, k = j & 255;
            wt2[j] = f2b(W2[k * 64 + n]);
        } else if (idx < 57344) {                // Wp: [64,128] -> wtp[n*64+k]
            int j = idx - 49152;
            int n = j >> 6, k = j & 63;
            wtp[j] = f2b(Wp[k * 128 + n]);
        }
    } else if (b < 225 + cx) {
        long long n128 = (long long)N * 128;
        long long idx = ((long long)(b - 225) * 256 + t) * 8;
        if (idx + 7 < n128) {
            float4 v0 = *reinterpret_cast<const float4*>(&x[idx]);
            float4 v1 = *reinterpret_cast<const float4*>(&x[idx + 4]);
            ushort o[8] = { f2b(v0.x), f2b(v0.y), f2b(v0.z), f2b(v0.w),
                            f2b(v1.x), f2b(v1.y), f2b(v1.z), f2b(v1.w) };
            uint4 pk;
            pk.x = (uint)o[0] | ((uint)o[1] << 16);
            pk.y = (uint)o[2] | ((uint)o[3] << 16);
            pk.z = (uint)o[4] | ((uint)o[5] << 16);
            pk.w = (uint)o[6] | ((uint)o[7] << 16);
            *reinterpret_cast<uint4*>(&xb[idx]) = pk;
        } else {
            for (long long q = idx; q < n128; ++q) xb[q] = f2b(x[q]);
        }
    } else {
        bool f64 = detect_f64(ei, E, (long long)N);
        int i = (b - 225 - cx) * 256 + t;
        int ET = E + N;
        if (i < ET) {
            int s, d;
            get_edge(ei, i, E, f64, s, d);
            atomicAdd(&deg[d], 1);
        }
    }
}

// ---------------- hierarchical scan ----------------
__global__ void scan1_kernel(const int* __restrict__ deg, int N, int* __restrict__ bsum)
{
    int b = blockIdx.x, t = threadIdx.x;
    int base = b * 4096 + t * 16;
    int s = 0;
    #pragma unroll
    for (int k = 0; k < 16; k += 4) {
        int idx = base + k;
        if (idx + 3 < N) {
            int4 v = *reinterpret_cast<const int4*>(&deg[idx]);
            s += v.x + v.y + v.z + v.w;
        } else {
            for (int q = 0; q < 4; ++q) if (idx + q < N) s += deg[idx + q];
        }
    }
    #pragma unroll
    for (int off = 1; off < 64; off <<= 1) s += __shfl_xor(s, off);
    __shared__ int wsum[4];
    if ((t & 63) == 0) wsum[t >> 6] = s;
    __syncthreads();
    if (t == 0) bsum[b] = wsum[0] + wsum[1] + wsum[2] + wsum[3];
}

__global__ void scan2_kernel(const int* __restrict__ bsum, int nb, int* __restrict__ bpre)
{
    if (threadIdx.x == 0) {
        int r = 0;
        for (int i = 0; i < nb; ++i) { bpre[i] = r; r += bsum[i]; }
        bpre[nb] = r;
    }
}

__global__ void scan3_kernel(const int* __restrict__ deg, int N,
                             const int* __restrict__ bpre, int nb,
                             int* __restrict__ rowptr, int* __restrict__ fillptr)
{
    int b = blockIdx.x, t = threadIdx.x;
    int base = b * 4096 + t * 16;
    int loc[16];
    int s = 0;
    #pragma unroll
    for (int k = 0; k < 16; ++k) {
        int idx = base + k;
        int d = (idx < N) ? deg[idx] : 0;
        loc[k] = s; s += d;
    }
    int lane = t & 63;
    int incl = s;
    #pragma unroll
    for (int off = 1; off < 64; off <<= 1) {
        int v = __shfl_up(incl, off);
        if (lane >= off) incl += v;
    }
    __shared__ int wsum[4];
    if (lane == 63) wsum[t >> 6] = incl;
    __syncthreads();
    int woff = 0;
    int w = t >> 6;
    for (int i = 0; i < w; ++i) woff += wsum[i];
    int off0 = bpre[b] + woff + incl - s;
    #pragma unroll
    for (int k = 0; k < 16; ++k) {
        int idx = base + k;
        if (idx < N) { rowptr[idx] = off0 + loc[k]; fillptr[idx] = off0 + loc[k]; }
    }
    if (b == 0 && t == 0) rowptr[N] = bpre[nb];
}

__global__ void fill_kernel(const void* ei, int E, int N, int* fillptr, int* esrc)
{
    bool f64 = detect_f64(ei, E, (long long)N);
    int i = blockIdx.x * blockDim.x + threadIdx.x;
    int ET = E + N;
    if (i >= ET) return;
    int s, d;
    get_edge(ei, i, E, f64, s, d);
    int pos = atomicAdd(&fillptr[d], 1);
    esrc[pos] = s;
}

// ---------------- MFMA bf16 GEMM: C[M,NC] = A[M,K] @ Bt[NC,K]^T ----------------
// ATT: 1 = GEMM1: row-major C; 8-head att dots -> as/ad row-major [M][8]
//      2 = GEMM2: C in slabs [gc>>5][M][32]; 1-head 64-col dots (LDS reduce)
template<int ATYPE, int OMODE, int ATT>
__global__ __launch_bounds__(256) void mgemm_kernel(const void* __restrict__ Ap,
    const ushort* __restrict__ Bt, void* __restrict__ Cp, int M, int K, int NC,
    const float* __restrict__ S, const float* __restrict__ Cc,
    const float* __restrict__ att_s, const float* __restrict__ att_d,
    float* __restrict__ as_out, float* __restrict__ ad_out)
{
    const int BM = 128, LDA = 72;
    __shared__ __align__(16) ushort As[BM][LDA];
    __shared__ __align__(16) ushort Bs[64][LDA];
    __shared__ float red[128][2];
    int t = threadIdx.x;
    int m0 = blockIdx.x * BM, n0 = blockIdx.y * 64;
    int w = t >> 6, l = t & 63;
    int wm = w >> 1, wn = w & 1;
    int r16 = l & 15, kg = l >> 4;

    f32x4 acc[4][2];
    #pragma unroll
    for (int mi = 0; mi < 4; ++mi)
        #pragma unroll
        for (int ni = 0; ni < 2; ++ni)
            acc[mi][ni] = (f32x4){0.f, 0.f, 0.f, 0.f};

    for (int kb = 0; kb < K; kb += 64) {
        if (ATYPE == 0) {
            const float* A = (const float*)Ap;
            #pragma unroll
            for (int p = 0; p < 8; ++p) {
                int r = (t >> 4) + p * 16, c4 = (t & 15) * 4;
                int gm = m0 + r;
                float4 v = (gm < M) ? *reinterpret_cast<const float4*>(&A[(size_t)gm * K + kb + c4])
                                    : make_float4(0.f, 0.f, 0.f, 0.f);
                ushort4 u; u.x = f2b(v.x); u.y = f2b(v.y); u.z = f2b(v.z); u.w = f2b(v.w);
                *reinterpret_cast<ushort4*>(&As[r][c4]) = u;
            }
        } else {
            const ushort* A = (const ushort*)Ap;
            #pragma unroll
            for (int p = 0; p < 4; ++p) {
                int r = (t >> 3) + p * 32, c8 = (t & 7) * 8;
                int gm = m0 + r;
                uint4 v = (gm < M) ? *reinterpret_cast<const uint4*>(&A[(size_t)gm * K + kb + c8])
                                   : make_uint4(0u, 0u, 0u, 0u);
                *reinterpret_cast<uint4*>(&As[r][c8]) = v;
            }
        }
        #pragma unroll
        for (int p = 0; p < 2; ++p) {
            int r = (t >> 3) + p * 32, c8 = (t & 7) * 8;
            uint4 v = *reinterpret_cast<const uint4*>(&Bt[(size_t)(n0 + r) * K + kb + c8]);
            *reinterpret_cast<uint4*>(&Bs[r][c8]) = v;
        }
        __syncthreads();
        #pragma unroll
        for (int kk = 0; kk < 2; ++kk) {
            bf16x8 bB[2], bA[4];
            #pragma unroll
            for (int ni = 0; ni < 2; ++ni)
                bB[ni] = *reinterpret_cast<const bf16x8*>(&Bs[wn * 32 + ni * 16 + r16][kk * 32 + kg * 8]);
            #pragma unroll
            for (int mi = 0; mi < 4; ++mi)
                bA[mi] = *reinterpret_cast<const bf16x8*>(&As[wm * 64 + mi * 16 + r16][kk * 32 + kg * 8]);
            #pragma unroll
            for (int mi = 0; mi < 4; ++mi)
                #pragma unroll
                for (int ni = 0; ni < 2; ++ni)
                    acc[mi][ni] = __builtin_amdgcn_mfma_f32_16x16x32_bf16(bA[mi], bB[ni], acc[mi][ni], 0, 0, 0);
        }
        __syncthreads();
    }
    #pragma unroll
    for (int mi = 0; mi < 4; ++mi) {
        #pragma unroll
        for (int ni = 0; ni < 2; ++ni) {
            #pragma unroll
            for (int rg = 0; rg < 4; ++rg) {
                int gm = m0 + wm * 64 + mi * 16 + kg * 4 + rg;
                int gc = n0 + wn * 32 + ni * 16 + r16;
                if (gm < M) {
                    float v = acc[mi][ni][rg];
                    if (OMODE == 0) {
                        size_t idx = (ATT == 2)
                            ? ((size_t)(gc >> 5) * M + gm) * 32 + (gc & 31)   // 2-slab layout
                            : (size_t)gm * NC + gc;                          // row-major
                        ((ushort*)Cp)[idx] = f2b(v);
                    } else {
                        ((float*)Cp)[(size_t)gm * NC + gc] = v * S[gc] + Cc[gc];
                    }
                }
            }
        }
    }
    if (ATT) {
        float cs0 = att_s[n0 + wn * 32 + r16], cs1 = att_s[n0 + wn * 32 + 16 + r16];
        float cd0 = att_d[n0 + wn * 32 + r16], cd1 = att_d[n0 + wn * 32 + 16 + r16];
        float sp[4][4], dp[4][4];
        #pragma unroll
        for (int mi = 0; mi < 4; ++mi)
            #pragma unroll
            for (int rg = 0; rg < 4; ++rg) {
                sp[mi][rg] = acc[mi][0][rg] * cs0 + acc[mi][1][rg] * cs1;
                dp[mi][rg] = acc[mi][0][rg] * cd0 + acc[mi][1][rg] * cd1;
            }
        #pragma unroll
        for (int off = 1; off < 16; off <<= 1)
            #pragma unroll
            for (int mi = 0; mi < 4; ++mi)
                #pragma unroll
                for (int rg = 0; rg < 4; ++rg) {
                    sp[mi][rg] += __shfl_xor(sp[mi][rg], off);
                    dp[mi][rg] += __shfl_xor(dp[mi][rg], off);
                }
        if (ATT == 1) {
            int head = (n0 >> 5) + wn;
            if (r16 == 0) {
                #pragma unroll
                for (int mi = 0; mi < 4; ++mi)
                    #pragma unroll
                    for (int rg = 0; rg < 4; ++rg) {
                        int gm = m0 + wm * 64 + mi * 16 + kg * 4 + rg;
                        if (gm < M) {
                            as_out[(size_t)gm * 8 + head] = sp[mi][rg];   // row-major [M][8]
                            ad_out[(size_t)gm * 8 + head] = dp[mi][rg];
                        }
                    }
            }
        } else {
            if (wn == 1 && r16 == 0) {
                #pragma unroll
                for (int mi = 0; mi < 4; ++mi)
                    #pragma unroll
                    for (int rg = 0; rg < 4; ++rg) {
                        int r = wm * 64 + mi * 16 + kg * 4 + rg;
                        red[r][0] = sp[mi][rg];
                        red[r][1] = dp[mi][rg];
                    }
            }
            __syncthreads();
            if (wn == 0 && r16 == 0) {
                #pragma unroll
                for (int mi = 0; mi < 4; ++mi)
                    #pragma unroll
                    for (int rg = 0; rg < 4; ++rg) {
                        int r = wm * 64 + mi * 16 + kg * 4 + rg;
                        int gm = m0 + r;
                        if (gm < M) {
                            as_out[gm] = sp[mi][rg] + red[r][0];
                            ad_out[gm] = dp[mi][rg] + red[r][1];
                        }
                    }
            }
        }
    }
}

// ---------------- layer-1 aggregation as row-window MFMA SpMM ----------------
// Block = 16-node group g. Windows of K=32 consecutive CSR edges.
// C[16 nodes][256 feats] += A[16x32] x B[32x256]:
//   A[i][k] = w_k (unnormalized alpha, head = feat-tile/2) iff dst(k)==i else 0
//   B[k][f] = h1[src(k)][f]  (gathered, 512B/edge coalesced)
// Normalization is linear: scale by 1/den[node][head] in the epilogue.
// Verified fragment maps (from mgemm): A[row=l&15][k=8*(l>>4)+j],
// B elem j = B[k=8*(l>>4)+j][col=l&15+16*tile], C row=4*(l>>4)+rg, col=l&15.
__global__ __launch_bounds__(256) void spmm1_kernel(
    const ushort* __restrict__ h1,      // [N][256] bf16
    const float* __restrict__ as1,      // [N][8]
    const float* __restrict__ ad1,      // [N][8]
    const int* __restrict__ rowptr,
    const int* __restrict__ esrc,
    const float* __restrict__ par,      // S1 = par[0..256), C1 = par[256..512)
    ushort* __restrict__ outb, int N)   // h1b [N][256]
{
    __shared__ ushort B_lds[32][264];       // [slot][feat] + pad
    __shared__ ushort A_lds[8][16][48];     // [head][node][slot] + pad
    __shared__ float  den_lds[16][8];
    __shared__ int    rowp[17];
    __shared__ int    src_lds[32];
    int t = threadIdx.x;
    int g = blockIdx.x;
    int n0 = g * 16;

    if (t < 17) rowp[t] = rowptr[min(n0 + t, N)];
    if (t < 128) ((float*)den_lds)[t] = 0.f;
    // zero A (6144 ushorts, 24/thread, 48B aligned per thread)
    {
        ushort* A0 = &A_lds[0][0][0];
        uint4 z = make_uint4(0u, 0u, 0u, 0u);
        *reinterpret_cast<uint4*>(A0 + t * 24 + 0)  = z;
        *reinterpret_cast<uint4*>(A0 + t * 24 + 8)  = z;
        *reinterpret_cast<uint4*>(A0 + t * 24 + 16) = z;
    }
    __syncthreads();

    int e0 = rowp[0], e1 = rowp[16];
    int lane = t & 63;
    int wv = t >> 6;                  // wave: feats [64*wv, 64*wv+64)
    int r16 = lane & 15, kg = lane >> 4;
    int slot = t >> 3, hh = t & 7;    // A-build assignment

    f32x4 acc[4];
    #pragma unroll
    for (int i = 0; i < 4; ++i) acc[i] = (f32x4){0.f, 0.f, 0.f, 0.f};

    int pz_row = -1;                  // previously-written A row for (hh, slot)

    for (int cb = e0; cb < e1; cb += 32) {
        int cnt = min(32, e1 - cb);
        // ---- build phase: zero prev A entry, write new, den, src ----
        if (pz_row >= 0) A_lds[hh][pz_row][slot] = 0;
        pz_row = -1;
        {
            int sl_src = 0;
            if (slot < cnt) {
                int ge = cb + slot;
                sl_src = esrc[ge];
                int r = 0;
                while (r < 15 && ge >= rowp[r + 1]) ++r;
                float wval = __expf(lrelu_f(as1[(size_t)sl_src * 8 + hh] +
                                            ad1[(size_t)(n0 + r) * 8 + hh]));
                A_lds[hh][r][slot] = f2b(wval);
                atomicAdd(&den_lds[r][hh], wval);
                pz_row = r;
            }
            if (hh == 0) src_lds[slot] = sl_src;
        }
        __syncthreads();
        // ---- gather phase: 32 edges x 512B -> B_lds ----
        #pragma unroll
        for (int rr = 0; rr < 4; ++rr) {
            int idx = t + rr * 256;           // 1024 chunks of 16B
            int e = idx >> 5, c = idx & 31;   // feats 8c..8c+7 of edge e
            uint4 v = *reinterpret_cast<const uint4*>(&h1[(size_t)src_lds[e] * 256 + c * 8]);
            *reinterpret_cast<uint4*>(&B_lds[e][c * 8]) = v;
        }
        __syncthreads();
        // ---- MFMA phase ----
        bf16x8 a0 = *reinterpret_cast<const bf16x8*>(&A_lds[2 * wv][r16][kg * 8]);
        bf16x8 a1 = *reinterpret_cast<const bf16x8*>(&A_lds[2 * wv + 1][r16][kg * 8]);
        #pragma unroll
        for (int tt = 0; tt < 4; ++tt) {
            int col = wv * 64 + tt * 16 + r16;
            union { bf16x8 v; ushort u[8]; } bb;
            #pragma unroll
            for (int j = 0; j < 8; ++j) bb.u[j] = B_lds[kg * 8 + j][col];
            acc[tt] = __builtin_amdgcn_mfma_f32_16x16x32_bf16((tt < 2) ? a0 : a1, bb.v, acc[tt], 0, 0, 0);
        }
        __syncthreads();   // before next window overwrites A/B
    }

    // ---- epilogue: normalize, BN+ELU, bf16 store ----
    #pragma unroll
    for (int tt = 0; tt < 4; ++tt) {
        int head = 2 * wv + (tt >> 1);
        int col = wv * 64 + tt * 16 + r16;
        float Sv = par[col], Cv = par[256 + col];
        #pragma unroll
        for (int rg = 0; rg < 4; ++rg) {
            int row = kg * 4 + rg;
            int n = n0 + row;
            if (n < N) {
                float inv = 1.f / (den_lds[row][head] + 1e-16f);
                float v = elu_f(acc[tt][rg] * inv * Sv + Cv);
                outb[(size_t)n * 256 + col] = f2b(v);
            }
        }
    }
}

// ---------------- aggregation layer 2: register-direct (r12, unchanged) ----------------
template<int NS, bool SATT>
__global__ void agg_kernel(const ushort* __restrict__ hs,
                           const float* __restrict__ ast, const float* __restrict__ adt,
                           const int* __restrict__ rowptr, const int* __restrict__ esrc,
                           const float* __restrict__ Sv, const float* __restrict__ Cv,
                           ushort* __restrict__ outb, int N)
{
    int s = blockIdx.x & (NS - 1);
    int wslot = threadIdx.x >> 6;
    int lane = threadIdx.x & 63;
    int qq = lane >> 4;
    int row = wslot * 4 + qq;
    int n = (int)(blockIdx.x / NS) * 16 + row;
    bool active = (n < N);
    int beg = 0, end = 0;
    float adv = 0.f;
    if (active) {
        beg = rowptr[n];
        end = rowptr[n + 1];
        adv = SATT ? adt[(size_t)s * N + n] : adt[n];
    }
    const float* as_s = SATT ? (ast + (size_t)s * N) : ast;
    const char* slabc = (const char*)(hs + (size_t)s * N * 32);
    int sub = (lane >> 3) & 1;
    uint eoff = (uint)(lane & 7) * 8u;
    float den = 0.f;
    float acc[4] = {0.f, 0.f, 0.f, 0.f};

    auto body = [&](float av, uint2 r) {
        float w = __expf(lrelu_f(av + adv));
        den += w;
        union { uint u; float f; } c;
        c.u = r.x << 16;         acc[0] += w * c.f;
        c.u = r.x & 0xffff0000u; acc[1] += w * c.f;
        c.u = r.y << 16;         acc[2] += w * c.f;
        c.u = r.y & 0xffff0000u; acc[3] += w * c.f;
    };

    int e = beg + sub;
    for (; e + 6 < end; e += 8) {
        int s0 = esrc[e], s1 = esrc[e + 2], s2 = esrc[e + 4], s3 = esrc[e + 6];
        float a0 = as_s[s0], a1 = as_s[s1], a2 = as_s[s2], a3 = as_s[s3];
        uint2 r0 = *reinterpret_cast<const uint2*>(slabc + ((uint)s0 * 64u + eoff));
        uint2 r1 = *reinterpret_cast<const uint2*>(slabc + ((uint)s1 * 64u + eoff));
        uint2 r2 = *reinterpret_cast<const uint2*>(slabc + ((uint)s2 * 64u + eoff));
        uint2 r3 = *reinterpret_cast<const uint2*>(slabc + ((uint)s3 * 64u + eoff));
        body(a0, r0); body(a1, r1); body(a2, r2); body(a3, r3);
    }
    for (; e < end; e += 2) {
        int s0 = esrc[e];
        float a0 = as_s[s0];
        uint2 r0 = *reinterpret_cast<const uint2*>(slabc + ((uint)s0 * 64u + eoff));
        body(a0, r0);
    }

    den += __shfl_xor(den, 1, 64);
    den += __shfl_xor(den, 2, 64);
    den += __shfl_xor(den, 4, 64);
    den += __shfl_xor(den, 8, 64);
    #pragma unroll
    for (int f = 0; f < 4; ++f) acc[f] += __shfl_xor(acc[f], 8, 64);
    if (active && sub == 0) {
        float inv = 8.f / (den + 8e-16f);
        int f = s * 32 + (lane & 7) * 4;
        float4 Sc = *reinterpret_cast<const float4*>(&Sv[f]);
        float4 Cc = *reinterpret_cast<const float4*>(&Cv[f]);
        ushort4 o;
        o.x = f2b(elu_f(acc[0] * inv * Sc.x + Cc.x));
        o.y = f2b(elu_f(acc[1] * inv * Sc.y + Cc.y));
        o.z = f2b(elu_f(acc[2] * inv * Sc.z + Cc.z));
        o.w = f2b(elu_f(acc[3] * inv * Sc.w + Cc.w));
        *reinterpret_cast<ushort4*>(&outb[(size_t)n * (NS * 32) + f]) = o;
    }
}

// ---------------- launch ----------------
extern "C" void kernel_launch(void* const* d_in, const int* in_sizes, int n_in,
                              void* d_out, int out_size, void* d_ws, size_t ws_size,
                              hipStream_t stream)
{
    const float* x      = (const float*)d_in[0];
    const void*  ei     = d_in[1];
    const float* W1     = (const float*)d_in[2];
    const float* a_src1 = (const float*)d_in[3];
    const float* a_dst1 = (const float*)d_in[4];
    const float* b1     = (const float*)d_in[5];
    const float* W2     = (const float*)d_in[6];
    const float* a_src2 = (const float*)d_in[7];
    const float* a_dst2 = (const float*)d_in[8];
    const float* b2     = (const float*)d_in[9];
    const float* Wp     = (const float*)d_in[10];
    const float* bp     = (const float*)d_in[11];
    const float* g1 = (const float*)d_in[12], *be1 = (const float*)d_in[13];
    const float* m1 = (const float*)d_in[14], *v1  = (const float*)d_in[15];
    const float* g2 = (const float*)d_in[16], *be2 = (const float*)d_in[17];
    const float* m2 = (const float*)d_in[18], *v2  = (const float*)d_in[19];
    const float* g3 = (const float*)d_in[20], *be3 = (const float*)d_in[21];
    const float* m3 = (const float*)d_in[22], *v3  = (const float*)d_in[23];
    float* out = (float*)d_out;

    const int N  = in_sizes[0] / 128;
    const int E  = in_sizes[1] / 2;
    const int ET = E + N;

    char* base = (char*)d_ws;
    size_t off = 0;
    auto alloc = [&](size_t bytes) -> char* {
        char* p = base + off;
        off += (bytes + 255) & ~(size_t)255;
        return p;
    };
    float*  par     = (float*)alloc(1024 * 4);
    int*    bsum    = (int*)alloc(256);
    int*    bpre    = (int*)alloc(256);
    int*    rowptr  = (int*)alloc((size_t)(N + 1) * 4);
    int*    fillptr = (int*)alloc((size_t)(N + 1) * 4);
    int*    esrc    = (int*)alloc((size_t)ET * 4);
    float*  as1     = (float*)alloc((size_t)N * 8 * 4);   // [N][8]
    float*  ad1     = (float*)alloc((size_t)N * 8 * 4);   // [N][8]
    float*  as2     = (float*)alloc((size_t)N * 4);
    float*  ad2     = (float*)alloc((size_t)N * 4);
    ushort* wt1     = (ushort*)alloc(256 * 128 * 2);
    ushort* wt2     = (ushort*)alloc(64 * 256 * 2);
    ushort* wtp     = (ushort*)alloc(128 * 64 * 2);
    ushort* xb      = (ushort*)alloc((size_t)N * 128 * 2);
    ushort* h1      = (ushort*)alloc((size_t)N * 256 * 2);  // row-major [N][256]
    ushort* h1b     = (ushort*)alloc((size_t)N * 256 * 2);  // row-major [N][256]
    ushort* h2      = (ushort*)alloc((size_t)N * 64 * 2);   // 2 slabs [s][N][32]
    ushort* g2buf   = (ushort*)alloc((size_t)N * 64 * 2);   // row-major [N][64]

    // 0) zero degree counters, then fused setup
    hipMemsetAsync(fillptr, 0, (N + 1) * sizeof(int), stream);
    int cx = (int)(((size_t)N * 128 + 2047) / 2048);
    int cblocks = (ET + 255) / 256;
    setup_kernel<<<225 + cx + cblocks, 256, 0, stream>>>(ei, E, N, fillptr, cx,
        x, xb, W1, W2, Wp, wt1, wt2, wtp,
        b1, b2, bp, g1, be1, m1, v1, g2, be2, m2, v2, g3, be3, m3, v3, par);

    // 1) CSR by dst
    int nb = (N + 4095) / 4096;
    scan1_kernel<<<nb, 256, 0, stream>>>(fillptr, N, bsum);
    scan2_kernel<<<1, 64, 0, stream>>>(bsum, nb, bpre);
    scan3_kernel<<<nb, 256, 0, stream>>>(fillptr, N, bpre, nb, rowptr, fillptr);
    fill_kernel<<<cblocks, 256, 0, stream>>>(ei, E, N, fillptr, esrc);

    // 2) layer 1: GEMM1 (att1 fused, row-major C + as/ad) -> MFMA SpMM agg
    int mb128 = (N + 127) / 128;
    int ngrp16 = (N + 15) / 16;
    mgemm_kernel<1, 0, 1><<<dim3(mb128, 4), 256, 0, stream>>>(xb, wt1, h1, N, 128, 256,
        nullptr, nullptr, a_src1, a_dst1, as1, ad1);
    spmm1_kernel<<<ngrp16, 256, 0, stream>>>(h1, as1, ad1, rowptr, esrc, par, h1b, N);

    // 3) layer 2: GEMM2 (att2 fused, 2-slab C) -> scalar agg2
    mgemm_kernel<1, 0, 2><<<dim3(mb128, 1), 256, 0, stream>>>(h1b, wt2, h2, N, 256, 64,
        nullptr, nullptr, a_src2, a_dst2, as2, ad2);
    agg_kernel<2, false><<<ngrp16 * 2, 256, 0, stream>>>(h2, as2, ad2, rowptr, esrc,
        par + 512, par + 576, g2buf, N);

    // 4) projection + BN3 folded
    mgemm_kernel<1, 1, 0><<<dim3(mb128, 2), 256, 0, stream>>>(g2buf, wtp, out, N, 64, 128,
        par + 640, par + 768, nullptr, nullptr, nullptr, nullptr);
}

// Round 14
// 278.580 us; speedup vs baseline: 1.0874x; 1.0874x over previous
//
#include <hip/hip_runtime.h>
#include <math.h>

#define NEG_SLOPE 0.2f
#define BN_EPS 1e-5f

typedef __bf16 bf16x8 __attribute__((ext_vector_type(8)));
typedef float  f32x4  __attribute__((ext_vector_type(4)));

__device__ __forceinline__ float elu_f(float x){ return x > 0.f ? x : expm1f(x); }
__device__ __forceinline__ float lrelu_f(float x){ return x > 0.f ? x : NEG_SLOPE * x; }

__device__ __forceinline__ float b2f(ushort u){
    union { uint i; float f; } v; v.i = (uint)u << 16; return v.f;
}
__device__ __forceinline__ ushort f2b(float f){
    union { float f; uint i; } v; v.f = f;
    uint r = v.i + 0x7FFFu + ((v.i >> 16) & 1u);   // RTN-even
    return (ushort)(r >> 16);
}

// per-wave int64-vs-int32 detect: one int64 load per lane + ballot.
__device__ __forceinline__ bool detect_f64(const void* ei, int E, long long N)
{
    const long long* p = (const long long*)ei;
    int lane = threadIdx.x & 63;
    long long v = p[lane % max(1, min(2 * E, 64))];
    bool bad = (v < 0 || v >= N);
    return __ballot(bad) == 0ull;
}

__device__ __forceinline__ void get_edge(const void* ei, int e, int E, bool f64, int& s, int& d)
{
    if (e < E) {
        if (f64) { const long long* p = (const long long*)ei; s = (int)p[e]; d = (int)p[E + e]; }
        else     { const int*       p = (const int*)ei;       s = p[e];      d = p[E + e]; }
    } else {
        s = d = e - E;   // self loops appended
    }
}

// ---------------- fused setup: BN fold + transposes + x->bf16 + degree count ----------------
__global__ void setup_kernel(const void* ei, int E, int N, int* deg, int cx,
    const float* __restrict__ x, ushort* __restrict__ xb,
    const float* __restrict__ W1, const float* __restrict__ W2, const float* __restrict__ Wp,
    ushort* __restrict__ wt1, ushort* __restrict__ wt2, ushort* __restrict__ wtp,
    const float* b1, const float* b2, const float* bp,
    const float* g1, const float* be1, const float* m1, const float* v1,
    const float* g2, const float* be2, const float* m2, const float* v2,
    const float* g3, const float* be3, const float* m3, const float* v3,
    float* par)
{
    int b = blockIdx.x, t = threadIdx.x;
    if (b == 0) {
        { float s = g1[t] * rsqrtf(v1[t] + BN_EPS); par[t] = s;        par[256 + t] = b1[t] * s + be1[t] - m1[t] * s; }
        if (t < 64)  { float s = g2[t] * rsqrtf(v2[t] + BN_EPS); par[512 + t] = s;  par[576 + t] = b2[t] * s + be2[t] - m2[t] * s; }
        if (t < 128) { float s = g3[t] * rsqrtf(v3[t] + BN_EPS); par[640 + t] = s;  par[768 + t] = bp[t] * s + be3[t] - m3[t] * s; }
    } else if (b <= 224) {
        int idx = (b - 1) * 256 + t;
        if (idx < 32768) {                       // W1: [128,256] -> wt1[n*128+k]
            int n = idx >> 7, k = idx & 127;
            wt1[idx] = f2b(W1[k * 256 + n]);
        } else if (idx < 49152) {                // W2: [256,64] -> wt2[n*256+k]
            int j = idx - 32768;
            int n = j >> 8, k = j & 255;
            wt2[j] = f2b(W2[k * 64 + n]);
        } else if (idx < 57344) {                // Wp: [64,128] -> wtp[n*64+k]
            int j = idx - 49152;
            int n = j >> 6, k = j & 63;
            wtp[j] = f2b(Wp[k * 128 + n]);
        }
    } else if (b < 225 + cx) {
        long long n128 = (long long)N * 128;
        long long idx = ((long long)(b - 225) * 256 + t) * 8;
        if (idx + 7 < n128) {
            float4 v0 = *reinterpret_cast<const float4*>(&x[idx]);
            float4 v1 = *reinterpret_cast<const float4*>(&x[idx + 4]);
            ushort o[8] = { f2b(v0.x), f2b(v0.y), f2b(v0.z), f2b(v0.w),
                            f2b(v1.x), f2b(v1.y), f2b(v1.z), f2b(v1.w) };
            uint4 pk;
            pk.x = (uint)o[0] | ((uint)o[1] << 16);
            pk.y = (uint)o[2] | ((uint)o[3] << 16);
            pk.z = (uint)o[4] | ((uint)o[5] << 16);
            pk.w = (uint)o[6] | ((uint)o[7] << 16);
            *reinterpret_cast<uint4*>(&xb[idx]) = pk;
        } else {
            for (long long q = idx; q < n128; ++q) xb[q] = f2b(x[q]);
        }
    } else {
        bool f64 = detect_f64(ei, E, (long long)N);
        int i = (b - 225 - cx) * 256 + t;
        int ET = E + N;
        if (i < ET) {
            int s, d;
            get_edge(ei, i, E, f64, s, d);
            atomicAdd(&deg[d], 1);
        }
    }
}

// ---------------- hierarchical scan (scan2 folded into scan3) ----------------
__global__ void scan1_kernel(const int* __restrict__ deg, int N, int* __restrict__ bsum)
{
    int b = blockIdx.x, t = threadIdx.x;
    int base = b * 4096 + t * 16;
    int s = 0;
    #pragma unroll
    for (int k = 0; k < 16; k += 4) {
        int idx = base + k;
        if (idx + 3 < N) {
            int4 v = *reinterpret_cast<const int4*>(&deg[idx]);
            s += v.x + v.y + v.z + v.w;
        } else {
            for (int q = 0; q < 4; ++q) if (idx + q < N) s += deg[idx + q];
        }
    }
    #pragma unroll
    for (int off = 1; off < 64; off <<= 1) s += __shfl_xor(s, off);
    __shared__ int wsum[4];
    if ((t & 63) == 0) wsum[t >> 6] = s;
    __syncthreads();
    if (t == 0) bsum[b] = wsum[0] + wsum[1] + wsum[2] + wsum[3];
}

__global__ void scan3_kernel(const int* __restrict__ deg, int N,
                             const int* __restrict__ bsum, int nb,
                             int* __restrict__ rowptr, int* __restrict__ fillptr)
{
    int b = blockIdx.x, t = threadIdx.x;
    // per-block prefix over bsum (nb <= 13: trivial serial sum)
    __shared__ int bpre_s;
    __shared__ int btot_s;
    if (t == 0) {
        int r = 0, tot = 0;
        for (int i = 0; i < nb; ++i) { if (i < b) r += bsum[i]; tot += bsum[i]; }
        bpre_s = r; btot_s = tot;
    }
    int base = b * 4096 + t * 16;
    int loc[16];
    int s = 0;
    #pragma unroll
    for (int k = 0; k < 16; ++k) {
        int idx = base + k;
        int d = (idx < N) ? deg[idx] : 0;
        loc[k] = s; s += d;
    }
    int lane = t & 63;
    int incl = s;
    #pragma unroll
    for (int off = 1; off < 64; off <<= 1) {
        int v = __shfl_up(incl, off);
        if (lane >= off) incl += v;
    }
    __shared__ int wsum[4];
    if (lane == 63) wsum[t >> 6] = incl;
    __syncthreads();
    int woff = 0;
    int w = t >> 6;
    for (int i = 0; i < w; ++i) woff += wsum[i];
    int off0 = bpre_s + woff + incl - s;
    #pragma unroll
    for (int k = 0; k < 16; ++k) {
        int idx = base + k;
        if (idx < N) { rowptr[idx] = off0 + loc[k]; fillptr[idx] = off0 + loc[k]; }
    }
    if (b == 0 && t == 0) rowptr[N] = btot_s;
}

__global__ void fill_kernel(const void* ei, int E, int N, int* fillptr, int* esrc)
{
    bool f64 = detect_f64(ei, E, (long long)N);
    int i = blockIdx.x * blockDim.x + threadIdx.x;
    int ET = E + N;
    if (i >= ET) return;
    int s, d;
    get_edge(ei, i, E, f64, s, d);
    int pos = atomicAdd(&fillptr[d], 1);
    esrc[pos] = s;
}

// ---------------- MFMA bf16 GEMM: C[M,NC] = A[M,K] @ Bt[NC,K]^T ----------------
// ATT: 1 = GEMM1: C in slabs [head][M][32]; att dots -> [head][M]
//      2 = GEMM2: C in slabs [gc>>5][M][32]; 1-head 64-col dots (LDS reduce)
template<int ATYPE, int OMODE, int ATT>
__global__ __launch_bounds__(256) void mgemm_kernel(const void* __restrict__ Ap,
    const ushort* __restrict__ Bt, void* __restrict__ Cp, int M, int K, int NC,
    const float* __restrict__ S, const float* __restrict__ Cc,
    const float* __restrict__ att_s, const float* __restrict__ att_d,
    float* __restrict__ as_out, float* __restrict__ ad_out)
{
    const int BM = 128, LDA = 72;
    __shared__ __align__(16) ushort As[BM][LDA];
    __shared__ __align__(16) ushort Bs[64][LDA];
    __shared__ float red[128][2];
    int t = threadIdx.x;
    int m0 = blockIdx.x * BM, n0 = blockIdx.y * 64;
    int w = t >> 6, l = t & 63;
    int wm = w >> 1, wn = w & 1;
    int r16 = l & 15, kg = l >> 4;

    f32x4 acc[4][2];
    #pragma unroll
    for (int mi = 0; mi < 4; ++mi)
        #pragma unroll
        for (int ni = 0; ni < 2; ++ni)
            acc[mi][ni] = (f32x4){0.f, 0.f, 0.f, 0.f};

    for (int kb = 0; kb < K; kb += 64) {
        if (ATYPE == 0) {
            const float* A = (const float*)Ap;
            #pragma unroll
            for (int p = 0; p < 8; ++p) {
                int r = (t >> 4) + p * 16, c4 = (t & 15) * 4;
                int gm = m0 + r;
                float4 v = (gm < M) ? *reinterpret_cast<const float4*>(&A[(size_t)gm * K + kb + c4])
                                    : make_float4(0.f, 0.f, 0.f, 0.f);
                ushort4 u; u.x = f2b(v.x); u.y = f2b(v.y); u.z = f2b(v.z); u.w = f2b(v.w);
                *reinterpret_cast<ushort4*>(&As[r][c4]) = u;
            }
        } else {
            const ushort* A = (const ushort*)Ap;
            #pragma unroll
            for (int p = 0; p < 4; ++p) {
                int r = (t >> 3) + p * 32, c8 = (t & 7) * 8;
                int gm = m0 + r;
                uint4 v = (gm < M) ? *reinterpret_cast<const uint4*>(&A[(size_t)gm * K + kb + c8])
                                   : make_uint4(0u, 0u, 0u, 0u);
                *reinterpret_cast<uint4*>(&As[r][c8]) = v;
            }
        }
        #pragma unroll
        for (int p = 0; p < 2; ++p) {
            int r = (t >> 3) + p * 32, c8 = (t & 7) * 8;
            uint4 v = *reinterpret_cast<const uint4*>(&Bt[(size_t)(n0 + r) * K + kb + c8]);
            *reinterpret_cast<uint4*>(&Bs[r][c8]) = v;
        }
        __syncthreads();
        #pragma unroll
        for (int kk = 0; kk < 2; ++kk) {
            bf16x8 bB[2], bA[4];
            #pragma unroll
            for (int ni = 0; ni < 2; ++ni)
                bB[ni] = *reinterpret_cast<const bf16x8*>(&Bs[wn * 32 + ni * 16 + r16][kk * 32 + kg * 8]);
            #pragma unroll
            for (int mi = 0; mi < 4; ++mi)
                bA[mi] = *reinterpret_cast<const bf16x8*>(&As[wm * 64 + mi * 16 + r16][kk * 32 + kg * 8]);
            #pragma unroll
            for (int mi = 0; mi < 4; ++mi)
                #pragma unroll
                for (int ni = 0; ni < 2; ++ni)
                    acc[mi][ni] = __builtin_amdgcn_mfma_f32_16x16x32_bf16(bA[mi], bB[ni], acc[mi][ni], 0, 0, 0);
        }
        __syncthreads();
    }
    #pragma unroll
    for (int mi = 0; mi < 4; ++mi) {
        #pragma unroll
        for (int ni = 0; ni < 2; ++ni) {
            #pragma unroll
            for (int rg = 0; rg < 4; ++rg) {
                int gm = m0 + wm * 64 + mi * 16 + kg * 4 + rg;
                int gc = n0 + wn * 32 + ni * 16 + r16;
                if (gm < M) {
                    float v = acc[mi][ni][rg];
                    if (OMODE == 0) {
                        size_t idx = (ATT >= 1)
                            ? ((size_t)(gc >> 5) * M + gm) * 32 + (gc & 31)   // slab layout
                            : (size_t)gm * NC + gc;
                        ((ushort*)Cp)[idx] = f2b(v);
                    } else {
                        ((float*)Cp)[(size_t)gm * NC + gc] = v * S[gc] + Cc[gc];
                    }
                }
            }
        }
    }
    if (ATT) {
        float cs0 = att_s[n0 + wn * 32 + r16], cs1 = att_s[n0 + wn * 32 + 16 + r16];
        float cd0 = att_d[n0 + wn * 32 + r16], cd1 = att_d[n0 + wn * 32 + 16 + r16];
        float sp[4][4], dp[4][4];
        #pragma unroll
        for (int mi = 0; mi < 4; ++mi)
            #pragma unroll
            for (int rg = 0; rg < 4; ++rg) {
                sp[mi][rg] = acc[mi][0][rg] * cs0 + acc[mi][1][rg] * cs1;
                dp[mi][rg] = acc[mi][0][rg] * cd0 + acc[mi][1][rg] * cd1;
            }
        #pragma unroll
        for (int off = 1; off < 16; off <<= 1)
            #pragma unroll
            for (int mi = 0; mi < 4; ++mi)
                #pragma unroll
                for (int rg = 0; rg < 4; ++rg) {
                    sp[mi][rg] += __shfl_xor(sp[mi][rg], off);
                    dp[mi][rg] += __shfl_xor(dp[mi][rg], off);
                }
        if (ATT == 1) {
            int head = (n0 >> 5) + wn;
            if (r16 == 0) {
                #pragma unroll
                for (int mi = 0; mi < 4; ++mi)
                    #pragma unroll
                    for (int rg = 0; rg < 4; ++rg) {
                        int gm = m0 + wm * 64 + mi * 16 + kg * 4 + rg;
                        if (gm < M) {
                            as_out[(size_t)head * M + gm] = sp[mi][rg];   // [head][M]
                            ad_out[(size_t)head * M + gm] = dp[mi][rg];
                        }
                    }
            }
        } else {
            if (wn == 1 && r16 == 0) {
                #pragma unroll
                for (int mi = 0; mi < 4; ++mi)
                    #pragma unroll
                    for (int rg = 0; rg < 4; ++rg) {
                        int r = wm * 64 + mi * 16 + kg * 4 + rg;
                        red[r][0] = sp[mi][rg];
                        red[r][1] = dp[mi][rg];
                    }
            }
            __syncthreads();
            if (wn == 0 && r16 == 0) {
                #pragma unroll
                for (int mi = 0; mi < 4; ++mi)
                    #pragma unroll
                    for (int rg = 0; rg < 4; ++rg) {
                        int r = wm * 64 + mi * 16 + kg * 4 + rg;
                        int gm = m0 + r;
                        if (gm < M) {
                            as_out[gm] = sp[mi][rg] + red[r][0];
                            ad_out[gm] = dp[mi][rg] + red[r][1];
                        }
                    }
            }
        }
    }
}

// ---------------- unified aggregation: XCD slab-sliced, register-direct gather ----------------
// NS slabs [s][N][32] bf16; slice s = blockIdx & (NS-1) -> fixed per XCD.
// Quarter (16 lanes) per node; sub-group of 8 lanes per edge (8B feats each).
// NO LDS / barriers / shfl in the hot loop; w recomputed redundantly per
// 8-lane group; den quarter-sum counts each w 8x -> inv = 8/den (exact).
template<int NS, bool SATT>
__global__ void agg_kernel(const ushort* __restrict__ hs,
                           const float* __restrict__ ast, const float* __restrict__ adt,
                           const int* __restrict__ rowptr, const int* __restrict__ esrc,
                           const float* __restrict__ Sv, const float* __restrict__ Cv,
                           ushort* __restrict__ outb, int N)
{
    int s = blockIdx.x & (NS - 1);
    int wslot = threadIdx.x >> 6;
    int lane = threadIdx.x & 63;
    int qq = lane >> 4;
    int row = wslot * 4 + qq;
    int n = (int)(blockIdx.x / NS) * 16 + row;
    bool active = (n < N);
    int beg = 0, end = 0;
    float adv = 0.f;
    if (active) {
        beg = rowptr[n];
        end = rowptr[n + 1];
        adv = SATT ? adt[(size_t)s * N + n] : adt[n];
    }
    const float* as_s = SATT ? (ast + (size_t)s * N) : ast;
    const char* slabc = (const char*)(hs + (size_t)s * N * 32);
    int sub = (lane >> 3) & 1;
    uint eoff = (uint)(lane & 7) * 8u;
    float den = 0.f;
    float acc[4] = {0.f, 0.f, 0.f, 0.f};

    auto body = [&](float av, uint2 r) {
        float w = __expf(lrelu_f(av + adv));
        den += w;
        union { uint u; float f; } c;
        c.u = r.x << 16;         acc[0] += w * c.f;
        c.u = r.x & 0xffff0000u; acc[1] += w * c.f;
        c.u = r.y << 16;         acc[2] += w * c.f;
        c.u = r.y & 0xffff0000u; acc[3] += w * c.f;
    };

    int e = beg + sub;
    for (; e + 6 < end; e += 8) {
        int s0 = esrc[e], s1 = esrc[e + 2], s2 = esrc[e + 4], s3 = esrc[e + 6];
        float a0 = as_s[s0], a1 = as_s[s1], a2 = as_s[s2], a3 = as_s[s3];
        uint2 r0 = *reinterpret_cast<const uint2*>(slabc + ((uint)s0 * 64u + eoff));
        uint2 r1 = *reinterpret_cast<const uint2*>(slabc + ((uint)s1 * 64u + eoff));
        uint2 r2 = *reinterpret_cast<const uint2*>(slabc + ((uint)s2 * 64u + eoff));
        uint2 r3 = *reinterpret_cast<const uint2*>(slabc + ((uint)s3 * 64u + eoff));
        body(a0, r0); body(a1, r1); body(a2, r2); body(a3, r3);
    }
    for (; e < end; e += 2) {
        int s0 = esrc[e];
        float a0 = as_s[s0];
        uint2 r0 = *reinterpret_cast<const uint2*>(slabc + ((uint)s0 * 64u + eoff));
        body(a0, r0);
    }

    den += __shfl_xor(den, 1, 64);
    den += __shfl_xor(den, 2, 64);
    den += __shfl_xor(den, 4, 64);
    den += __shfl_xor(den, 8, 64);
    #pragma unroll
    for (int f = 0; f < 4; ++f) acc[f] += __shfl_xor(acc[f], 8, 64);
    if (active && sub == 0) {
        float inv = 8.f / (den + 8e-16f);
        int f = s * 32 + (lane & 7) * 4;
        float4 Sc = *reinterpret_cast<const float4*>(&Sv[f]);
        float4 Cc = *reinterpret_cast<const float4*>(&Cv[f]);
        ushort4 o;
        o.x = f2b(elu_f(acc[0] * inv * Sc.x + Cc.x));
        o.y = f2b(elu_f(acc[1] * inv * Sc.y + Cc.y));
        o.z = f2b(elu_f(acc[2] * inv * Sc.z + Cc.z));
        o.w = f2b(elu_f(acc[3] * inv * Sc.w + Cc.w));
        *reinterpret_cast<ushort4*>(&outb[(size_t)n * (NS * 32) + f]) = o;
    }
}

// ---------------- launch ----------------
extern "C" void kernel_launch(void* const* d_in, const int* in_sizes, int n_in,
                              void* d_out, int out_size, void* d_ws, size_t ws_size,
                              hipStream_t stream)
{
    const float* x      = (const float*)d_in[0];
    const void*  ei     = d_in[1];
    const float* W1     = (const float*)d_in[2];
    const float* a_src1 = (const float*)d_in[3];
    const float* a_dst1 = (const float*)d_in[4];
    const float* b1     = (const float*)d_in[5];
    const float* W2     = (const float*)d_in[6];
    const float* a_src2 = (const float*)d_in[7];
    const float* a_dst2 = (const float*)d_in[8];
    const float* b2     = (const float*)d_in[9];
    const float* Wp     = (const float*)d_in[10];
    const float* bp     = (const float*)d_in[11];
    const float* g1 = (const float*)d_in[12], *be1 = (const float*)d_in[13];
    const float* m1 = (const float*)d_in[14], *v1  = (const float*)d_in[15];
    const float* g2 = (const float*)d_in[16], *be2 = (const float*)d_in[17];
    const float* m2 = (const float*)d_in[18], *v2  = (const float*)d_in[19];
    const float* g3 = (const float*)d_in[20], *be3 = (const float*)d_in[21];
    const float* m3 = (const float*)d_in[22], *v3  = (const float*)d_in[23];
    float* out = (float*)d_out;

    const int N  = in_sizes[0] / 128;
    const int E  = in_sizes[1] / 2;
    const int ET = E + N;

    char* base = (char*)d_ws;
    size_t off = 0;
    auto alloc = [&](size_t bytes) -> char* {
        char* p = base + off;
        off += (bytes + 255) & ~(size_t)255;
        return p;
    };
    float*  par     = (float*)alloc(1024 * 4);
    int*    bsum    = (int*)alloc(256);
    int*    rowptr  = (int*)alloc((size_t)(N + 1) * 4);
    int*    fillptr = (int*)alloc((size_t)(N + 1) * 4);
    int*    esrc    = (int*)alloc((size_t)ET * 4);
    float*  as1     = (float*)alloc((size_t)N * 8 * 4);   // [8][N]
    float*  ad1     = (float*)alloc((size_t)N * 8 * 4);   // [8][N]
    float*  as2     = (float*)alloc((size_t)N * 4);
    float*  ad2     = (float*)alloc((size_t)N * 4);
    ushort* wt1     = (ushort*)alloc(256 * 128 * 2);
    ushort* wt2     = (ushort*)alloc(64 * 256 * 2);
    ushort* wtp     = (ushort*)alloc(128 * 64 * 2);
    ushort* xb      = (ushort*)alloc((size_t)N * 128 * 2);
    ushort* h1      = (ushort*)alloc((size_t)N * 256 * 2);  // 8 slabs [s][N][32]
    ushort* h1b     = (ushort*)alloc((size_t)N * 256 * 2);  // row-major [N][256]
    ushort* h2      = (ushort*)alloc((size_t)N * 64 * 2);   // 2 slabs [s][N][32]
    ushort* g2buf   = (ushort*)alloc((size_t)N * 64 * 2);   // row-major [N][64]

    // 0) zero degree counters, then fused setup
    hipMemsetAsync(fillptr, 0, (N + 1) * sizeof(int), stream);
    int cx = (int)(((size_t)N * 128 + 2047) / 2048);
    int cblocks = (ET + 255) / 256;
    setup_kernel<<<225 + cx + cblocks, 256, 0, stream>>>(ei, E, N, fillptr, cx,
        x, xb, W1, W2, Wp, wt1, wt2, wtp,
        b1, b2, bp, g1, be1, m1, v1, g2, be2, m2, v2, g3, be3, m3, v3, par);

    // 1) CSR by dst (scan2 folded into scan3)
    int nb = (N + 4095) / 4096;
    scan1_kernel<<<nb, 256, 0, stream>>>(fillptr, N, bsum);
    scan3_kernel<<<nb, 256, 0, stream>>>(fillptr, N, bsum, nb, rowptr, fillptr);
    fill_kernel<<<cblocks, 256, 0, stream>>>(ei, E, N, fillptr, esrc);

    // 2) layer 1: GEMM1 (att1 fused, 8-slab C) -> agg1 (register-direct)
    int mb128 = (N + 127) / 128;
    int ngrp16 = (N + 15) / 16;
    mgemm_kernel<1, 0, 1><<<dim3(mb128, 4), 256, 0, stream>>>(xb, wt1, h1, N, 128, 256,
        nullptr, nullptr, a_src1, a_dst1, as1, ad1);
    agg_kernel<8, true><<<ngrp16 * 8, 256, 0, stream>>>(h1, as1, ad1, rowptr, esrc,
        par, par + 256, h1b, N);

    // 3) layer 2: GEMM2 (att2 fused, 2-slab C) -> agg2
    mgemm_kernel<1, 0, 2><<<dim3(mb128, 1), 256, 0, stream>>>(h1b, wt2, h2, N, 256, 64,
        nullptr, nullptr, a_src2, a_dst2, as2, ad2);
    agg_kernel<2, false><<<ngrp16 * 2, 256, 0, stream>>>(h2, as2, ad2, rowptr, esrc,
        par + 512, par + 576, g2buf, N);

    // 4) projection + BN3 folded
    mgemm_kernel<1, 1, 0><<<dim3(mb128, 2), 256, 0, stream>>>(g2buf, wtp, out, N, 64, 128,
        par + 640, par + 768, nullptr, nullptr, nullptr, nullptr);
}